// Round 9
// baseline (181.530 us; speedup 1.0000x reference)
//
#include <hip/hip_runtime.h>
#include <hip/hip_bf16.h>

typedef __attribute__((ext_vector_type(4))) float f32x4;
typedef __attribute__((ext_vector_type(8))) short s16x8;
typedef __attribute__((ext_vector_type(4))) short s16x4;

#define DEV static __device__ __forceinline__

// fp32 -> bf16 round-to-nearest-even
DEV unsigned short f2bf(float f) {
    unsigned int u = __builtin_bit_cast(unsigned int, f);
    u += 0x7fffu + ((u >> 16) & 1u);
    return (unsigned short)(u >> 16);
}

#if __has_builtin(__builtin_amdgcn_exp2f)
#define EXP2(x) __builtin_amdgcn_exp2f(x)
#else
#define EXP2(x) exp2f(x)
#endif

// pack two fp32 -> two truncated bf16 in one dword (low short = a, high = b)
DEV unsigned int pack2(float a, float b) {
#if __has_builtin(__builtin_amdgcn_perm)
    return __builtin_amdgcn_perm(__builtin_bit_cast(unsigned int, b),
                                 __builtin_bit_cast(unsigned int, a), 0x07060302u);
#else
    return (__builtin_bit_cast(unsigned int, a) >> 16) |
           (__builtin_bit_cast(unsigned int, b) & 0xffff0000u);
#endif
}

// 8 bf16 from LDS via two 8B reads (strides with only 8B alignment)
DEV s16x8 ld8(const unsigned short* p) {
    s16x4 lo = *(const s16x4*)(p);
    s16x4 hi = *(const s16x4*)(p + 4);
    return __builtin_shufflevector(lo, hi, 0, 1, 2, 3, 4, 5, 6, 7);
}
// 16B-aligned single b128 read
DEV s16x8 ld8a(const unsigned short* p) { return *(const s16x8*)p; }

DEV f32x4 mfma16(s16x8 a, s16x8 b, f32x4 c) {
    return __builtin_amdgcn_mfma_f32_16x16x32_bf16(a, b, c, 0, 0, 0);
}

// async global->LDS, 16B per lane; lds dest = wave-uniform base + lane*16
DEV void glds16(const unsigned short* g, unsigned short* l) {
    __builtin_amdgcn_global_load_lds(
        (const __attribute__((address_space(1))) unsigned int*)g,
        (__attribute__((address_space(3))) unsigned int*)l, 16, 0, 0);
}

// ---------------------------------------------------------------------------
// fp32 -> bf16 bulk cast over three disjoint regions (one launch)
// ---------------------------------------------------------------------------
__global__ __launch_bounds__(256) void convf2b3(
        const float* __restrict__ s0, unsigned short* __restrict__ d0, int n40,
        const float* __restrict__ s1, unsigned short* __restrict__ d1, int n41,
        const float* __restrict__ s2, unsigned short* __restrict__ d2, int n42) {
    int i = blockIdx.x * 256 + threadIdx.x;
    if (i < n40) {
        float4 v = ((const float4*)s0)[i];
        s16x4 o = {(short)f2bf(v.x), (short)f2bf(v.y), (short)f2bf(v.z), (short)f2bf(v.w)};
        ((s16x4*)d0)[i] = o;
    } else if (i - n40 < n41) {
        int j = i - n40;
        float4 v = ((const float4*)s1)[j];
        s16x4 o = {(short)f2bf(v.x), (short)f2bf(v.y), (short)f2bf(v.z), (short)f2bf(v.w)};
        ((s16x4*)d1)[j] = o;
    } else if (i - n40 - n41 < n42) {
        int j = i - n40 - n41;
        float4 v = ((const float4*)s2)[j];
        s16x4 o = {(short)f2bf(v.x), (short)f2bf(v.y), (short)f2bf(v.z), (short)f2bf(v.w)};
        ((s16x4*)d2)[j] = o;
    }
}

__global__ __launch_bounds__(256) void convf2b(const float* __restrict__ s,
                                               unsigned short* __restrict__ d, int n4) {
    int i = blockIdx.x * 256 + threadIdx.x;
    if (i < n4) {
        float4 v = ((const float4*)s)[i];
        s16x4 o = {(short)f2bf(v.x), (short)f2bf(v.y), (short)f2bf(v.z), (short)f2bf(v.w)};
        ((s16x4*)d)[i] = o;
    }
}

// ---------------------------------------------------------------------------
// QKV projection (proven 128x128 2-phase, 768 blocks = 3/CU, ~815 TF):
// C[4096][3072] = Xb[4096][1024](bf16) * Wq[3072][1024](bf16)^T
// ---------------------------------------------------------------------------
__global__ __launch_bounds__(512) void qkv_gemm(
        const unsigned short* __restrict__ Xb, const unsigned short* __restrict__ Wq,
        unsigned short* __restrict__ q_ws, unsigned short* __restrict__ k_ws,
        unsigned short* __restrict__ v_ws) {
    __shared__ unsigned short As[2][128 * 32];
    __shared__ unsigned short Bs[2][128 * 32];
    const int tid = threadIdx.x, lane = tid & 63, wave = tid >> 6;  // 0..7
    const int l15 = lane & 15, l4 = lane >> 4;
    const int wm = (wave >> 1) * 32, wn = (wave & 1) * 64;
    const int m0 = blockIdx.y * 128, n0 = blockIdx.x * 128;

    f32x4 acc[2][4];
    for (int i = 0; i < 2; i++)
        for (int j = 0; j < 4; j++) acc[i][j] = (f32x4){0.f, 0.f, 0.f, 0.f};

    const unsigned short* aptr = &Xb[(size_t)(m0 + wave * 16 + (lane >> 2)) * 1024 + (lane & 3) * 8];
    const unsigned short* bptr = &Wq[(size_t)(n0 + wave * 16 + (lane >> 2)) * 1024 + (lane & 3) * 8];

    for (int k0 = 0; k0 < 1024; k0 += 64) {
        __syncthreads();
        for (int c = 0; c < 2; c++) {
            glds16(aptr + k0 + c * 32, &As[c][(wave * 16) * 32]);
            glds16(bptr + k0 + c * 32, &Bs[c][(wave * 16) * 32]);
        }
        __syncthreads();
        for (int c = 0; c < 2; c++) {
            s16x8 af[2], bf[4];
            for (int mt = 0; mt < 2; mt++) af[mt] = ld8a(&As[c][(wm + mt * 16 + l15) * 32 + l4 * 8]);
            for (int nt = 0; nt < 4; nt++) bf[nt] = ld8a(&Bs[c][(wn + nt * 16 + l15) * 32 + l4 * 8]);
            for (int mt = 0; mt < 2; mt++)
                for (int nt = 0; nt < 4; nt++)
                    acc[mt][nt] = mfma16(af[mt], bf[nt], acc[mt][nt]);
        }
    }

    // epilogue (C/D layout: row=(lane>>4)*4+reg, col=lane&15)
    const int gnb = n0 + wn;  // 64-aligned -> one (which, head) per wave
    const int which = gnb >> 10, h = (gnb >> 6) & 15;
    const int bidx = m0 >> 11, tb = m0 & 2047;
    if (which == 2) {
        // V transposed: v_ws[bh][dh][t], 4 consecutive t per lane -> 8B store
        unsigned short* dst = v_ws + (size_t)(bidx * 16 + h) * 64 * 2048;
        for (int mt = 0; mt < 2; mt++) {
            int t = tb + wm + mt * 16 + l4 * 4;
            for (int nt = 0; nt < 4; nt++) {
                int dh = nt * 16 + l15;
                s16x4 pp;
                for (int r = 0; r < 4; r++) pp[r] = (short)f2bf(acc[mt][nt][r]);
                *(s16x4*)&dst[(size_t)dh * 2048 + t] = pp;
            }
        }
    } else {
        unsigned short* dst = ((which == 0) ? q_ws : k_ws) + (size_t)(bidx * 16 + h) * 2048 * 64;
        // q folded scale: Dh^-0.5 * log2(e) so attention uses raw exp2
        const float sc = (which == 0) ? 0.18033688f : 1.0f;
        for (int mt = 0; mt < 2; mt++) {
            int t0 = tb + wm + mt * 16 + l4 * 4;
            for (int nt = 0; nt < 4; nt++) {
                int dh = nt * 16 + l15;
                for (int r = 0; r < 4; r++)
                    dst[(size_t)(t0 + r) * 64 + dh] = f2bf(acc[mt][nt][r] * sc);
            }
        }
    }
}

// ---------------------------------------------------------------------------
// Causal flash attention v14 = v13 structure + complementary pairing +
// 3-deep counted-vmcnt pipeline.
//   4 waves x 32 contiguous q-rows; block = one 128-row chunk c.
//   Pairing: id = bh8 + 8*(g + 4*pp), c = pp<8 ? 15-pp : pp-8 -> co-resident
//   pair (k, k+256) has chunks c and 15-c = uniform 36 tiles/CU (v13's
//   longest-first ordering anti-paired 48-vs-20: that was the regression).
//   K/V 3-deep, stage(r+2) after barrier, wait vmcnt(4) (4 glds/wave/stage,
//   1 stage in flight) -> each load covered by ~2 compute rounds.
//   P: 16 rows/wave LDP=64 + XOR swizzle, sequential qs0/qs1 round-trip,
//   V-fragments register-staged once shared by both qs. LDS 56 KB.
// ---------------------------------------------------------------------------
__global__ __launch_bounds__(256, 4) void attn(
        const unsigned short* __restrict__ q_ws, const unsigned short* __restrict__ k_ws,
        const unsigned short* __restrict__ v_ws, unsigned short* __restrict__ ao) {
    __shared__ unsigned short Ks[3][2][64 * 32];  // [buf][d-half][key][32 d]   24 KB
    __shared__ unsigned short Vt[3][2][64 * 32];  // [buf][key-half][d][32 key] 24 KB
    __shared__ unsigned short Ps[4 * 16 * 64];    // per-wave P (16 rows x 64)   8 KB
    const int tid = threadIdx.x, lane = tid & 63, wave = tid >> 6;  // 0..3
    const int l15 = lane & 15, l4 = lane >> 4;
    const int xf = (l15 >> 1) & 3;     // K/V read-slot swizzle (matched on glds src)
    const int sw = (l15 & 7) << 3;     // P-region XOR swizzle (shorts)

    // id = bh8 + 8*(g + 4*pp); complementary pairing across the 256-stride
    const int id = blockIdx.x;
    const int bh8 = id & 7, rest = id >> 3;
    const int g = rest & 3, pp = rest >> 2;        // g in [0,4), pp in [0,16)
    const int bh = bh8 + 8 * g, b = bh >> 4, h = bh & 15;
    const int c = (pp < 8) ? (15 - pp) : (pp - 8);
    const int qrow = c * 128 + wave * 32;
    const int T = 2 * c + 2;                       // key-tiles: 2..32

    const size_t base = (size_t)bh * 2048 * 64;
    const unsigned short* vtb = v_ws + (size_t)bh * 64 * 2048;  // V^T [d][t]
    unsigned short* Pw = &Ps[wave * 1024];

    // staging: wave stages 16 K rows + 16 V^T rows, both 32-wide halves.
    // Source col pre-swizzled to match the (l4^xf) read swizzle.
    const int seg = wave, srow = lane >> 2;
    const int scol = ((lane & 3) ^ ((lane >> 3) & 3)) * 8;  // shorts
    const unsigned short* kg = &k_ws[base + (size_t)(seg * 16 + srow) * 64 + scol];
    const unsigned short* vg = &vtb[(size_t)(seg * 16 + srow) * 2048 + scol];

    auto stage = [&](int tau, int buf) {  // 4 glds16: tile tau -> buf
        const unsigned short* kgt = kg + (size_t)tau * 4096;
        const unsigned short* vgt = vg + tau * 64;
        unsigned short* kd = &Ks[buf][0][seg * 512];
        unsigned short* vd = &Vt[buf][0][seg * 512];
        glds16(kgt,      kd);
        glds16(kgt + 32, kd + 2048);
        glds16(vgt,      vd);
        glds16(vgt + 32, vd + 2048);
    };

    // Q fragments (B-operand: n=q, k=d); q pre-scaled by Dh^-0.5*log2e.
    s16x8 qf[2][2];
#pragma unroll
    for (int qs = 0; qs < 2; qs++)
#pragma unroll
        for (int c2 = 0; c2 < 2; c2++)
            qf[qs][c2] = ld8a(&q_ws[base + (size_t)(qrow + qs * 16 + l15) * 64 + c2 * 32 + l4 * 8]);
    asm volatile("s_waitcnt vmcnt(0)" ::: "memory");  // clean slate for counts

    f32x4 o[2][4];
    float lsum[2] = {0.f, 0.f};
#pragma unroll
    for (int qs = 0; qs < 2; qs++)
#pragma unroll
        for (int i = 0; i < 4; i++) o[qs][i] = (f32x4){0.f, 0.f, 0.f, 0.f};

    // prologue: tiles 0 and 1 (T >= 2 always)
    stage(0, 0);
    stage(1, 1);

    for (int r = 0; r < T; ++r) {
        if (r + 1 < T) asm volatile("s_waitcnt vmcnt(4)" ::: "memory");  // tile r done
        else           asm volatile("s_waitcnt vmcnt(0)" ::: "memory");
        __builtin_amdgcn_s_barrier();                 // buf (r-1)%3 free
        if (r + 2 < T) stage(r + 2, (r + 2) % 3);
        const int k0 = r * 64;
        if (k0 < qrow + 32) {  // wave-uniform (waves 0-1 idle only final round)
            const unsigned short* kb = &Ks[r % 3][0][0];
            const unsigned short* vb = &Vt[r % 3][0][0];

            // ---- S^T = K*Q^T; each K frag feeds both qs ----
            f32x4 st[2][4];
#pragma unroll
            for (int qs = 0; qs < 2; qs++)
#pragma unroll
                for (int ks = 0; ks < 4; ks++) st[qs][ks] = (f32x4){0.f, 0.f, 0.f, 0.f};
            __builtin_amdgcn_s_setprio(1);
#pragma unroll
            for (int c2 = 0; c2 < 2; c2++)
#pragma unroll
                for (int ks = 0; ks < 4; ks++) {
                    s16x8 kf = ld8a(&kb[c2 * 2048 + (ks * 16 + l15) * 32 + (l4 ^ xf) * 8]);
                    st[0][ks] = mfma16(kf, qf[0][c2], st[0][ks]);
                    st[1][ks] = mfma16(kf, qf[1][c2], st[1][ks]);
                }
            __builtin_amdgcn_s_setprio(0);

            // ---- per-qs: mask + exp2 + pack -> P (shared 16-row buffer) ----
            s16x8 pf[2][2];
#pragma unroll
            for (int qs = 0; qs < 2; qs++) {
                const int qb = qrow + qs * 16;
                if (k0 + 63 > qb) {  // wave-uniform diagonal check
                    int qg = qb + l15;
#pragma unroll
                    for (int ks = 0; ks < 4; ks++)
#pragma unroll
                        for (int rr = 0; rr < 4; rr++) {
                            int kgi = k0 + ks * 16 + l4 * 4 + rr;
                            if (kgi > qg) st[qs][ks][rr] = -1e30f;
                        }
                }
                float part = 0.f;
#pragma unroll
                for (int ks = 0; ks < 4; ks++) {
                    float p0 = EXP2(st[qs][ks][0]);
                    float p1 = EXP2(st[qs][ks][1]);
                    float p2 = EXP2(st[qs][ks][2]);
                    float p3 = EXP2(st[qs][ks][3]);
                    part += (p0 + p1) + (p2 + p3);
                    unsigned int u0 = pack2(p0, p1), u1 = pack2(p2, p3);
                    *(uint2*)&Pw[l15 * 64 + ((ks * 16 + l4 * 4) ^ sw)] = (uint2){u0, u1};
                }
                lsum[qs] += part;
                // read back this qs's P fragments before next qs overwrites the
                // buffer (per-wave DS pipe is in-order -> WAR safe)
#pragma unroll
                for (int c2 = 0; c2 < 2; c2++)
                    pf[qs][c2] = ld8(&Pw[l15 * 64 + ((c2 * 32 + l4 * 8) ^ sw)]);
            }

            // ---- O^T += V^T * P^T; V frags register-staged, shared by both qs ----
            __builtin_amdgcn_s_setprio(1);
#pragma unroll
            for (int c2 = 0; c2 < 2; c2++)
#pragma unroll
                for (int ds = 0; ds < 4; ds++) {
                    s16x8 vf = ld8a(&vb[c2 * 2048 + (ds * 16 + l15) * 32 + (l4 ^ xf) * 8]);
                    o[0][ds] = mfma16(vf, pf[0][c2], o[0][ds]);
                    o[1][ds] = mfma16(vf, pf[1][c2], o[1][ds]);
                }
            __builtin_amdgcn_s_setprio(0);
        }
    }

    // ---- epilogue: per qs reduce l across l4, normalize, transpose, store ----
    int qr = lane >> 2, qt = lane & 3;
    const int swr = (qr & 7) << 3;
#pragma unroll
    for (int qs = 0; qs < 2; qs++) {
        float t = lsum[qs];
        t += __shfl_xor(t, 16, 64);
        t += __shfl_xor(t, 32, 64);
        float inv = 1.f / t;
#pragma unroll
        for (int ds = 0; ds < 4; ds++) {
            s16x4 pp2;
#pragma unroll
            for (int r = 0; r < 4; r++) pp2[r] = (short)f2bf(o[qs][ds][r] * inv);
            *(s16x4*)&Pw[l15 * 64 + ((ds * 16 + l4 * 4) ^ sw)] = pp2;  // Ow[q][d]
        }
        size_t orow = ((size_t)b * 2048 + qrow + qs * 16 + qr) * 1024 + h * 64 + qt * 16;
        *(s16x8*)&ao[orow]     = ld8(&Pw[qr * 64 + ((qt * 16) ^ swr)]);
        *(s16x8*)&ao[orow + 8] = ld8(&Pw[qr * 64 + ((qt * 16 + 8) ^ swr)]);
    }
}

// ---------------------------------------------------------------------------
// Output projection v2 (round-6 win, frozen): OUT = AO(bf16) * Wo(bf16)^T.
// 64(M)x128(N) block tile, 256 thr / 4 waves, wave tile 32x64, BK=64.
// Grid (8 n, 64 m) = 512 blocks = 2/CU.
// ---------------------------------------------------------------------------
__global__ __launch_bounds__(256) void out_gemm(
        const unsigned short* __restrict__ A, const unsigned short* __restrict__ Bm,
        float* __restrict__ OUT) {
    __shared__ unsigned short As[2][64 * 32];
    __shared__ unsigned short Bs[2][128 * 32];
    const int tid = threadIdx.x, lane = tid & 63, wave = tid >> 6;  // 0..3
    const int l15 = lane & 15, l4 = lane >> 4;
    const int wm = (wave >> 1) * 32, wn = (wave & 1) * 64;
    const int m0 = blockIdx.y * 64, n0 = blockIdx.x * 128;

    f32x4 acc[2][4];
    for (int i = 0; i < 2; i++)
        for (int j = 0; j < 4; j++) acc[i][j] = (f32x4){0.f, 0.f, 0.f, 0.f};

    // wave stages A rows [wave*16,+16) and B rows [wave*32,+32)
    const unsigned short* aptr = &A[(size_t)(m0 + wave * 16 + (lane >> 2)) * 1024 + (lane & 3) * 8];
    const unsigned short* bptr = &Bm[(size_t)(n0 + wave * 32 + (lane >> 2)) * 1024 + (lane & 3) * 8];

    for (int k0 = 0; k0 < 1024; k0 += 64) {
        __syncthreads();
        for (int c = 0; c < 2; c++) {
            glds16(aptr + k0 + c * 32, &As[c][(wave * 16) * 32]);
            glds16(bptr + k0 + c * 32, &Bs[c][(wave * 32) * 32]);
            glds16(bptr + k0 + c * 32 + 16 * 1024, &Bs[c][(wave * 32 + 16) * 32]);
        }
        __syncthreads();
        for (int c = 0; c < 2; c++) {
            s16x8 af[2], bf[4];
            for (int mt = 0; mt < 2; mt++) af[mt] = ld8a(&As[c][(wm + mt * 16 + l15) * 32 + l4 * 8]);
            for (int nt = 0; nt < 4; nt++) bf[nt] = ld8a(&Bs[c][(wn + nt * 16 + l15) * 32 + l4 * 8]);
            for (int mt = 0; mt < 2; mt++)
                for (int nt = 0; nt < 4; nt++)
                    acc[mt][nt] = mfma16(af[mt], bf[nt], acc[mt][nt]);
        }
    }

    for (int mt = 0; mt < 2; mt++)
        for (int nt = 0; nt < 4; nt++)
            for (int r = 0; r < 4; r++) {
                int gm = m0 + wm + mt * 16 + l4 * 4 + r;
                int gn = n0 + wn + nt * 16 + l15;
                OUT[(size_t)gm * 1024 + gn] = acc[mt][nt][r];
            }
}

// ---------------------------------------------------------------------------
extern "C" void kernel_launch(void* const* d_in, const int* in_sizes, int n_in,
                              void* d_out, int out_size, void* d_ws, size_t ws_size,
                              hipStream_t stream) {
    (void)in_sizes; (void)n_in; (void)out_size;
    const float* x    = (const float*)d_in[0];   // [2,2048,1024]
    const float* Wqkv = (const float*)d_in[1];   // [3072,1024]
    const float* Wout = (const float*)d_in[2];   // [1024,1024]
    float* out = (float*)d_out;                  // [2,2048,1024] fp32

    // workspace layout (first 32 MB):
    //   [0,8M)   q_ws [bh][T][64]
    //   [8,16M)  k_ws [bh][T][64]
    //   [16,24M) v_ws TRANSPOSED [bh][64][T]
    //   [24,32M) Xb (bf16 X) during qkv; then attn output AO
    //   [32M,34M) wob (Wout bf16) if ws_size permits
    // d_out (16 MB fp32) doubles as scratch for Wqkv-bf16 (6 MB).
    unsigned short* q_ws = (unsigned short*)d_ws;
    unsigned short* k_ws = q_ws + (size_t)4 * 1024 * 1024;
    unsigned short* v_ws = k_ws + (size_t)4 * 1024 * 1024;
    unsigned short* xb   = v_ws + (size_t)4 * 1024 * 1024;  // 8 MB
    unsigned short* ao   = xb;                              // born in attn, xb dead
    unsigned short* wqb  = (unsigned short*)d_out;          // 6 MB scratch in d_out

    const int n4x = 2 * 2048 * 1024 / 4, n4w = 3072 * 1024 / 4, n4o = 1024 * 1024 / 4;
    const bool merged = ws_size >= (size_t)35 * 1024 * 1024;
    unsigned short* wob = merged ? (q_ws + (size_t)16 * 1024 * 1024)  // d_ws + 32 MB
                                 : q_ws;                              // reuse after attn

    if (merged) {
        convf2b3<<<(n4x + n4w + n4o + 255) / 256, 256, 0, stream>>>(
            x, xb, n4x, Wqkv, wqb, n4w, Wout, wob, n4o);
    } else {
        convf2b3<<<(n4x + n4w + 255) / 256, 256, 0, stream>>>(
            x, xb, n4x, Wqkv, wqb, n4w, Wout, wob, 0);
    }
    qkv_gemm<<<dim3(24, 32), 512, 0, stream>>>(xb, wqb, q_ws, k_ws, v_ws);
    attn<<<dim3(512), 256, 0, stream>>>(q_ws, k_ws, v_ws, ao);
    if (!merged) convf2b<<<1024, 256, 0, stream>>>(Wout, wob, n4o);
    out_gemm<<<dim3(8, 64), 256, 0, stream>>>(ao, wob, out);
}

// Round 10
// 162.751 us; speedup vs baseline: 1.1154x; 1.1154x over previous
//
#include <hip/hip_runtime.h>
#include <hip/hip_bf16.h>

typedef __attribute__((ext_vector_type(4))) float f32x4;
typedef __attribute__((ext_vector_type(8))) short s16x8;
typedef __attribute__((ext_vector_type(4))) short s16x4;

#define DEV static __device__ __forceinline__

// fp32 -> bf16 round-to-nearest-even
DEV unsigned short f2bf(float f) {
    unsigned int u = __builtin_bit_cast(unsigned int, f);
    u += 0x7fffu + ((u >> 16) & 1u);
    return (unsigned short)(u >> 16);
}

#if __has_builtin(__builtin_amdgcn_exp2f)
#define EXP2(x) __builtin_amdgcn_exp2f(x)
#else
#define EXP2(x) exp2f(x)
#endif

// pack two fp32 -> two truncated bf16 in one dword (low short = a, high = b)
DEV unsigned int pack2(float a, float b) {
#if __has_builtin(__builtin_amdgcn_perm)
    return __builtin_amdgcn_perm(__builtin_bit_cast(unsigned int, b),
                                 __builtin_bit_cast(unsigned int, a), 0x07060302u);
#else
    return (__builtin_bit_cast(unsigned int, a) >> 16) |
           (__builtin_bit_cast(unsigned int, b) & 0xffff0000u);
#endif
}

// 8 bf16 from LDS via two 8B reads (strides with only 8B alignment)
DEV s16x8 ld8(const unsigned short* p) {
    s16x4 lo = *(const s16x4*)(p);
    s16x4 hi = *(const s16x4*)(p + 4);
    return __builtin_shufflevector(lo, hi, 0, 1, 2, 3, 4, 5, 6, 7);
}
// 16B-aligned single b128 read
DEV s16x8 ld8a(const unsigned short* p) { return *(const s16x8*)p; }

DEV f32x4 mfma16(s16x8 a, s16x8 b, f32x4 c) {
    return __builtin_amdgcn_mfma_f32_16x16x32_bf16(a, b, c, 0, 0, 0);
}

// async global->LDS, 16B per lane; lds dest = wave-uniform base + lane*16
DEV void glds16(const unsigned short* g, unsigned short* l) {
    __builtin_amdgcn_global_load_lds(
        (const __attribute__((address_space(1))) unsigned int*)g,
        (__attribute__((address_space(3))) unsigned int*)l, 16, 0, 0);
}

// ---------------------------------------------------------------------------
// fp32 -> bf16 bulk cast over three disjoint regions (one launch)
// ---------------------------------------------------------------------------
__global__ __launch_bounds__(256) void convf2b3(
        const float* __restrict__ s0, unsigned short* __restrict__ d0, int n40,
        const float* __restrict__ s1, unsigned short* __restrict__ d1, int n41,
        const float* __restrict__ s2, unsigned short* __restrict__ d2, int n42) {
    int i = blockIdx.x * 256 + threadIdx.x;
    if (i < n40) {
        float4 v = ((const float4*)s0)[i];
        s16x4 o = {(short)f2bf(v.x), (short)f2bf(v.y), (short)f2bf(v.z), (short)f2bf(v.w)};
        ((s16x4*)d0)[i] = o;
    } else if (i - n40 < n41) {
        int j = i - n40;
        float4 v = ((const float4*)s1)[j];
        s16x4 o = {(short)f2bf(v.x), (short)f2bf(v.y), (short)f2bf(v.z), (short)f2bf(v.w)};
        ((s16x4*)d1)[j] = o;
    } else if (i - n40 - n41 < n42) {
        int j = i - n40 - n41;
        float4 v = ((const float4*)s2)[j];
        s16x4 o = {(short)f2bf(v.x), (short)f2bf(v.y), (short)f2bf(v.z), (short)f2bf(v.w)};
        ((s16x4*)d2)[j] = o;
    }
}

__global__ __launch_bounds__(256) void convf2b(const float* __restrict__ s,
                                               unsigned short* __restrict__ d, int n4) {
    int i = blockIdx.x * 256 + threadIdx.x;
    if (i < n4) {
        float4 v = ((const float4*)s)[i];
        s16x4 o = {(short)f2bf(v.x), (short)f2bf(v.y), (short)f2bf(v.z), (short)f2bf(v.w)};
        ((s16x4*)d)[i] = o;
    }
}

// ---------------------------------------------------------------------------
// QKV projection (proven 128x128 2-phase, 768 blocks = 3/CU, ~815 TF):
// C[4096][3072] = Xb[4096][1024](bf16) * Wq[3072][1024](bf16)^T
// ---------------------------------------------------------------------------
__global__ __launch_bounds__(512) void qkv_gemm(
        const unsigned short* __restrict__ Xb, const unsigned short* __restrict__ Wq,
        unsigned short* __restrict__ q_ws, unsigned short* __restrict__ k_ws,
        unsigned short* __restrict__ v_ws) {
    __shared__ unsigned short As[2][128 * 32];
    __shared__ unsigned short Bs[2][128 * 32];
    const int tid = threadIdx.x, lane = tid & 63, wave = tid >> 6;  // 0..7
    const int l15 = lane & 15, l4 = lane >> 4;
    const int wm = (wave >> 1) * 32, wn = (wave & 1) * 64;
    const int m0 = blockIdx.y * 128, n0 = blockIdx.x * 128;

    f32x4 acc[2][4];
    for (int i = 0; i < 2; i++)
        for (int j = 0; j < 4; j++) acc[i][j] = (f32x4){0.f, 0.f, 0.f, 0.f};

    const unsigned short* aptr = &Xb[(size_t)(m0 + wave * 16 + (lane >> 2)) * 1024 + (lane & 3) * 8];
    const unsigned short* bptr = &Wq[(size_t)(n0 + wave * 16 + (lane >> 2)) * 1024 + (lane & 3) * 8];

    for (int k0 = 0; k0 < 1024; k0 += 64) {
        __syncthreads();
        for (int c = 0; c < 2; c++) {
            glds16(aptr + k0 + c * 32, &As[c][(wave * 16) * 32]);
            glds16(bptr + k0 + c * 32, &Bs[c][(wave * 16) * 32]);
        }
        __syncthreads();
        for (int c = 0; c < 2; c++) {
            s16x8 af[2], bf[4];
            for (int mt = 0; mt < 2; mt++) af[mt] = ld8a(&As[c][(wm + mt * 16 + l15) * 32 + l4 * 8]);
            for (int nt = 0; nt < 4; nt++) bf[nt] = ld8a(&Bs[c][(wn + nt * 16 + l15) * 32 + l4 * 8]);
            for (int mt = 0; mt < 2; mt++)
                for (int nt = 0; nt < 4; nt++)
                    acc[mt][nt] = mfma16(af[mt], bf[nt], acc[mt][nt]);
        }
    }

    // epilogue (C/D layout: row=(lane>>4)*4+reg, col=lane&15)
    const int gnb = n0 + wn;  // 64-aligned -> one (which, head) per wave
    const int which = gnb >> 10, h = (gnb >> 6) & 15;
    const int bidx = m0 >> 11, tb = m0 & 2047;
    if (which == 2) {
        // V transposed: v_ws[bh][dh][t], 4 consecutive t per lane -> 8B store
        unsigned short* dst = v_ws + (size_t)(bidx * 16 + h) * 64 * 2048;
        for (int mt = 0; mt < 2; mt++) {
            int t = tb + wm + mt * 16 + l4 * 4;
            for (int nt = 0; nt < 4; nt++) {
                int dh = nt * 16 + l15;
                s16x4 pp;
                for (int r = 0; r < 4; r++) pp[r] = (short)f2bf(acc[mt][nt][r]);
                *(s16x4*)&dst[(size_t)dh * 2048 + t] = pp;
            }
        }
    } else {
        unsigned short* dst = ((which == 0) ? q_ws : k_ws) + (size_t)(bidx * 16 + h) * 2048 * 64;
        // q folded scale: Dh^-0.5 * log2(e) so attention uses raw exp2
        const float sc = (which == 0) ? 0.18033688f : 1.0f;
        for (int mt = 0; mt < 2; mt++) {
            int t0 = tb + wm + mt * 16 + l4 * 4;
            for (int nt = 0; nt < 4; nt++) {
                int dh = nt * 16 + l15;
                for (int r = 0; r < 4; r++)
                    dst[(size_t)(t0 + r) * 64 + dh] = f2bf(acc[mt][nt][r] * sc);
            }
        }
    }
}

// ---------------------------------------------------------------------------
// Causal flash attention v12 (best measured: round 6/7, ~37 us): split-key
// uniform schedule. Block handles chunk pair (p, 15-p), 128 rows each.
// T_lo = 2(p+1), T_hi = 2(16-p); T_lo + T_hi = 34 for every p.
// Waves 0-3 (group A): hi-chunk rows vs key-tiles 0..16.
// Waves 4-7 (group B): lo-chunk rows vs full causal range (T_lo tiles), then
//   hi-chunk rows vs tiles 17..T_hi-1. 17 uniform rounds for every wave ->
//   minimal critical-path round count (the variable that governs attn time).
// No-max softmax is linear -> partial (O, l) from disjoint key ranges add;
// merged through LDS after the loop. Two K/V streams, each 3-deep, counted
// vmcnt(4), raw s_barrier, setprio around MFMA. Grid 256 = 1 block/CU.
// ---------------------------------------------------------------------------
__global__ __launch_bounds__(512, 2) void attn(
        const unsigned short* __restrict__ q_ws, const unsigned short* __restrict__ k_ws,
        const unsigned short* __restrict__ v_ws, unsigned short* __restrict__ ao) {
    constexpr int LDP = 68;  // dword stride 34 -> cheap 2-way
    // manual carve: A-stream K/V, B-stream K/V (each [3][2][64*32]), then P
    __shared__ unsigned short lds[66560];
    unsigned short* KsA = lds;                // 12288 shorts
    unsigned short* VtA = lds + 12288;
    unsigned short* KsB = lds + 24576;
    unsigned short* VtB = lds + 36864;
    unsigned short* Ps  = lds + 49152;        // 8 waves x 32 rows x LDP

    const int tid = threadIdx.x, lane = tid & 63, wave = tid >> 6;  // 0..7
    const int l15 = lane & 15, l4 = lane >> 4;
    const int xf = (l15 >> 1) & 3;  // K/V read-slot swizzle (matched on glds src)

    const int id = blockIdx.x;
    const int bh8 = id & 7, rest = id >> 3;
    const int p = rest & 7, g = rest >> 3;     // p in [0,8), g in [0,4)
    const int bh = bh8 + 8 * g, b = bh >> 4, h = bh & 15;
    const bool isA = wave < 4;
    const int w4 = wave & 3;
    const int qrow_hi = (15 - p) * 128 + w4 * 32;
    const int qrow_lo = p * 128 + w4 * 32;
    const int Tlo = 2 * p + 2;                 // 2..16

    const size_t base = (size_t)bh * 2048 * 64;
    const unsigned short* vtb = v_ws + (size_t)bh * 64 * 2048;  // V^T [d][t]
    unsigned short* Pw = &Ps[wave * 32 * LDP];

    // staging: wave stages 16 K rows (seg) + 16 V^T rows, both 32-wide halves,
    // of ITS GROUP's stream. Source col pre-swizzled to match (l4^xf) read.
    const int seg = w4, srow = lane >> 2;
    const int scol = ((lane & 3) ^ ((lane >> 3) & 3)) * 8;  // shorts
    const unsigned short* kg = &k_ws[base + (size_t)(seg * 16 + srow) * 64 + scol];
    const unsigned short* vg = &vtb[(size_t)(seg * 16 + srow) * 2048 + scol];
    unsigned short* Ksm = isA ? KsA : KsB;
    unsigned short* Vtm = isA ? VtA : VtB;

    auto stage = [&](int tau, int buf) {  // 4 glds16, tile tau -> buf
        const unsigned short* kgt = kg + (size_t)tau * 4096;
        const unsigned short* vgt = vg + tau * 64;
        unsigned short* kd = Ksm + buf * 4096 + seg * 512;
        unsigned short* vd = Vtm + buf * 4096 + seg * 512;
        glds16(kgt,      kd);
        glds16(kgt + 32, kd + 2048);
        glds16(vgt,      vd);
        glds16(vgt + 32, vd + 2048);
    };
    auto myTile = [&](int x) { return (isA || x < Tlo) ? x : 17 + x - Tlo; };

    // Q fragments (B-operand: n=q, k=d); pre-scaled by Dh^-0.5*log2e.
    s16x8 qfh[2][2], qfl[2][2];
#pragma unroll
    for (int qs = 0; qs < 2; qs++)
#pragma unroll
        for (int c = 0; c < 2; c++)
            qfh[qs][c] = ld8a(&q_ws[base + (size_t)(qrow_hi + qs * 16 + l15) * 64 + c * 32 + l4 * 8]);
    if (!isA) {
#pragma unroll
        for (int qs = 0; qs < 2; qs++)
#pragma unroll
            for (int c = 0; c < 2; c++)
                qfl[qs][c] = ld8a(&q_ws[base + (size_t)(qrow_lo + qs * 16 + l15) * 64 + c * 32 + l4 * 8]);
    }
    asm volatile("s_waitcnt vmcnt(0)" ::: "memory");  // clean slate for counts

    f32x4 oh[2][4], ol[2][4];
    float lh[2] = {0.f, 0.f}, ll[2] = {0.f, 0.f};
#pragma unroll
    for (int qs = 0; qs < 2; qs++)
#pragma unroll
        for (int i = 0; i < 4; i++) {
            oh[qs][i] = (f32x4){0.f, 0.f, 0.f, 0.f};
            ol[qs][i] = (f32x4){0.f, 0.f, 0.f, 0.f};
        }

    auto compute = [&](const unsigned short* kb, const unsigned short* vb,
                       s16x8 (&qf)[2][2], f32x4 (&o)[2][4], float (&ls)[2],
                       int qrow, int k0) {
        // ---- S^T = K*Q^T (A: m=key, k=d); each K frag feeds both qs ----
        f32x4 st[2][4];
#pragma unroll
        for (int qs = 0; qs < 2; qs++)
#pragma unroll
            for (int ks = 0; ks < 4; ks++) st[qs][ks] = (f32x4){0.f, 0.f, 0.f, 0.f};
        __builtin_amdgcn_s_setprio(1);
#pragma unroll
        for (int c = 0; c < 2; c++)
#pragma unroll
            for (int ks = 0; ks < 4; ks++) {
                s16x8 kf = ld8a(&kb[c * 2048 + (ks * 16 + l15) * 32 + (l4 ^ xf) * 8]);
                st[0][ks] = mfma16(kf, qf[0][c], st[0][ks]);
                st[1][ks] = mfma16(kf, qf[1][c], st[1][ks]);
            }
        __builtin_amdgcn_s_setprio(0);

        // ---- causal mask (diag tiles only) + exp2 + pack P + l ----
#pragma unroll
        for (int qs = 0; qs < 2; qs++) {
            const int qb = qrow + qs * 16;
            if (k0 + 63 > qb) {  // wave-uniform diagonal check
                int qg = qb + l15;
#pragma unroll
                for (int ks = 0; ks < 4; ks++)
#pragma unroll
                    for (int rr = 0; rr < 4; rr++) {
                        int kgi = k0 + ks * 16 + l4 * 4 + rr;
                        if (kgi > qg) st[qs][ks][rr] = -1e30f;
                    }
            }
            float part = 0.f;
#pragma unroll
            for (int ks = 0; ks < 4; ks++) {
                float p0 = EXP2(st[qs][ks][0]);
                float p1 = EXP2(st[qs][ks][1]);
                float p2 = EXP2(st[qs][ks][2]);
                float p3 = EXP2(st[qs][ks][3]);
                part += (p0 + p1) + (p2 + p3);
                unsigned int u0 = pack2(p0, p1), u1 = pack2(p2, p3);
                *(uint2*)&Pw[(qs * 16 + l15) * LDP + ks * 16 + l4 * 4] = (uint2){u0, u1};
            }
            ls[qs] += part;
        }

        // ---- O^T += V^T * P^T; each V frag feeds both qs ----
        s16x8 pf[2][2];
#pragma unroll
        for (int qs = 0; qs < 2; qs++)
#pragma unroll
            for (int c = 0; c < 2; c++)
                pf[qs][c] = ld8(&Pw[(qs * 16 + l15) * LDP + c * 32 + l4 * 8]);
        __builtin_amdgcn_s_setprio(1);
#pragma unroll
        for (int c = 0; c < 2; c++)
#pragma unroll
            for (int ds = 0; ds < 4; ds++) {
                s16x8 vf = ld8a(&vb[c * 2048 + (ds * 16 + l15) * 32 + (l4 ^ xf) * 8]);
                o[0][ds] = mfma16(vf, pf[0][c], o[0][ds]);
                o[1][ds] = mfma16(vf, pf[1][c], o[1][ds]);
            }
        __builtin_amdgcn_s_setprio(0);
    };

    // prologue: tiles for rounds 0 and 1
    stage(myTile(0), 0);
    stage(myTile(1), 1);

    for (int r = 0; r < 17; ++r) {
        if (r < 16) asm volatile("s_waitcnt vmcnt(4)" ::: "memory");
        else        asm volatile("s_waitcnt vmcnt(0)" ::: "memory");
        __builtin_amdgcn_s_barrier();  // tile r visible; buf (r-1)%3 free
        if (r + 2 < 17) stage(myTile(r + 2), (r + 2) % 3);
        const unsigned short* kb = Ksm + (r % 3) * 4096;
        const unsigned short* vb = Vtm + (r % 3) * 4096;
        if (isA) {
            compute(kb, vb, qfh, oh, lh, qrow_hi, r * 64);       // always active
        } else if (r < Tlo) {
            if (r * 64 < qrow_lo + 16) compute(kb, vb, qfl, ol, ll, qrow_lo, r * 64);
        } else {
            const int k0 = (17 + r - Tlo) * 64;
            if (k0 < qrow_hi + 16) compute(kb, vb, qfh, oh, lh, qrow_hi, k0);
        }
    }

    // ---- merge hi-chunk partials (A keys 0..1087 + B keys 1088..) ----
    __syncthreads();  // all K/V reads done; stream area reusable
    float* mrg = (float*)lds;   // per B-wave: 8 f32x4-vecs x 64 lanes + 2x64 l
    f32x4* m4 = (f32x4*)mrg;
    if (!isA) {
#pragma unroll
        for (int qs = 0; qs < 2; qs++) {
#pragma unroll
            for (int ds = 0; ds < 4; ds++)
                m4[w4 * 544 + (qs * 4 + ds) * 64 + lane] = oh[qs][ds];
            mrg[w4 * 2176 + 2048 + qs * 64 + lane] = lh[qs];
        }
    }
    __syncthreads();

    auto epilogue = [&](f32x4 (&o)[2][4], float (&ls)[2], int qrow) {
#pragma unroll
        for (int qs = 0; qs < 2; qs++) {
            float t = ls[qs];
            t += __shfl_xor(t, 16, 64);
            t += __shfl_xor(t, 32, 64);
            float inv = 1.f / t;
#pragma unroll
            for (int ds = 0; ds < 4; ds++) {
                s16x4 pp;
#pragma unroll
                for (int r = 0; r < 4; r++) pp[r] = (short)f2bf(o[qs][ds][r] * inv);
                *(s16x4*)&Pw[(qs * 16 + l15) * LDP + ds * 16 + l4 * 4] = pp;  // Ow[q][d]
            }
        }
        int qr = lane >> 2, qt = lane & 3;
#pragma unroll
        for (int qs = 0; qs < 2; qs++) {
            size_t orow = ((size_t)b * 2048 + qrow + qs * 16 + qr) * 1024 + h * 64 + qt * 16;
            *(s16x8*)&ao[orow]     = ld8(&Pw[(qs * 16 + qr) * LDP + qt * 16]);
            *(s16x8*)&ao[orow + 8] = ld8(&Pw[(qs * 16 + qr) * LDP + qt * 16 + 8]);
        }
    };

    if (isA) {
#pragma unroll
        for (int qs = 0; qs < 2; qs++) {
#pragma unroll
            for (int ds = 0; ds < 4; ds++)
                oh[qs][ds] += m4[w4 * 544 + (qs * 4 + ds) * 64 + lane];
            lh[qs] += mrg[w4 * 2176 + 2048 + qs * 64 + lane];
        }
        epilogue(oh, lh, qrow_hi);
    } else {
        epilogue(ol, ll, qrow_lo);
    }
}

// ---------------------------------------------------------------------------
// Output projection v2 (round-6 win, frozen): OUT = AO(bf16) * Wo(bf16)^T.
// 64(M)x128(N) block tile, 256 thr / 4 waves, wave tile 32x64, BK=64.
// Grid (8 n, 64 m) = 512 blocks = 2/CU.
// ---------------------------------------------------------------------------
__global__ __launch_bounds__(256) void out_gemm(
        const unsigned short* __restrict__ A, const unsigned short* __restrict__ Bm,
        float* __restrict__ OUT) {
    __shared__ unsigned short As[2][64 * 32];
    __shared__ unsigned short Bs[2][128 * 32];
    const int tid = threadIdx.x, lane = tid & 63, wave = tid >> 6;  // 0..3
    const int l15 = lane & 15, l4 = lane >> 4;
    const int wm = (wave >> 1) * 32, wn = (wave & 1) * 64;
    const int m0 = blockIdx.y * 64, n0 = blockIdx.x * 128;

    f32x4 acc[2][4];
    for (int i = 0; i < 2; i++)
        for (int j = 0; j < 4; j++) acc[i][j] = (f32x4){0.f, 0.f, 0.f, 0.f};

    // wave stages A rows [wave*16,+16) and B rows [wave*32,+32)
    const unsigned short* aptr = &A[(size_t)(m0 + wave * 16 + (lane >> 2)) * 1024 + (lane & 3) * 8];
    const unsigned short* bptr = &Bm[(size_t)(n0 + wave * 32 + (lane >> 2)) * 1024 + (lane & 3) * 8];

    for (int k0 = 0; k0 < 1024; k0 += 64) {
        __syncthreads();
        for (int c = 0; c < 2; c++) {
            glds16(aptr + k0 + c * 32, &As[c][(wave * 16) * 32]);
            glds16(bptr + k0 + c * 32, &Bs[c][(wave * 32) * 32]);
            glds16(bptr + k0 + c * 32 + 16 * 1024, &Bs[c][(wave * 32 + 16) * 32]);
        }
        __syncthreads();
        for (int c = 0; c < 2; c++) {
            s16x8 af[2], bf[4];
            for (int mt = 0; mt < 2; mt++) af[mt] = ld8a(&As[c][(wm + mt * 16 + l15) * 32 + l4 * 8]);
            for (int nt = 0; nt < 4; nt++) bf[nt] = ld8a(&Bs[c][(wn + nt * 16 + l15) * 32 + l4 * 8]);
            for (int mt = 0; mt < 2; mt++)
                for (int nt = 0; nt < 4; nt++)
                    acc[mt][nt] = mfma16(af[mt], bf[nt], acc[mt][nt]);
        }
    }

    for (int mt = 0; mt < 2; mt++)
        for (int nt = 0; nt < 4; nt++)
            for (int r = 0; r < 4; r++) {
                int gm = m0 + wm + mt * 16 + l4 * 4 + r;
                int gn = n0 + wn + nt * 16 + l15;
                OUT[(size_t)gm * 1024 + gn] = acc[mt][nt][r];
            }
}

// ---------------------------------------------------------------------------
extern "C" void kernel_launch(void* const* d_in, const int* in_sizes, int n_in,
                              void* d_out, int out_size, void* d_ws, size_t ws_size,
                              hipStream_t stream) {
    (void)in_sizes; (void)n_in; (void)out_size;
    const float* x    = (const float*)d_in[0];   // [2,2048,1024]
    const float* Wqkv = (const float*)d_in[1];   // [3072,1024]
    const float* Wout = (const float*)d_in[2];   // [1024,1024]
    float* out = (float*)d_out;                  // [2,2048,1024] fp32

    // workspace layout (first 32 MB):
    //   [0,8M)   q_ws [bh][T][64]
    //   [8,16M)  k_ws [bh][T][64]
    //   [16,24M) v_ws TRANSPOSED [bh][64][T]
    //   [24,32M) Xb (bf16 X) during qkv; then attn output AO
    //   [32M,34M) wob (Wout bf16) if ws_size permits
    // d_out (16 MB fp32) doubles as scratch for Wqkv-bf16 (6 MB).
    unsigned short* q_ws = (unsigned short*)d_ws;
    unsigned short* k_ws = q_ws + (size_t)4 * 1024 * 1024;
    unsigned short* v_ws = k_ws + (size_t)4 * 1024 * 1024;
    unsigned short* xb   = v_ws + (size_t)4 * 1024 * 1024;  // 8 MB
    unsigned short* ao   = xb;                              // born in attn, xb dead
    unsigned short* wqb  = (unsigned short*)d_out;          // 6 MB scratch in d_out

    const int n4x = 2 * 2048 * 1024 / 4, n4w = 3072 * 1024 / 4, n4o = 1024 * 1024 / 4;
    const bool merged = ws_size >= (size_t)35 * 1024 * 1024;
    unsigned short* wob = merged ? (q_ws + (size_t)16 * 1024 * 1024)  // d_ws + 32 MB
                                 : q_ws;                              // reuse after attn

    if (merged) {
        convf2b3<<<(n4x + n4w + n4o + 255) / 256, 256, 0, stream>>>(
            x, xb, n4x, Wqkv, wqb, n4w, Wout, wob, n4o);
    } else {
        convf2b3<<<(n4x + n4w + 255) / 256, 256, 0, stream>>>(
            x, xb, n4x, Wqkv, wqb, n4w, Wout, wob, 0);
    }
    qkv_gemm<<<dim3(24, 32), 512, 0, stream>>>(xb, wqb, q_ws, k_ws, v_ws);
    attn<<<dim3(256), 512, 0, stream>>>(q_ws, k_ws, v_ws, ao);
    if (!merged) convf2b<<<1024, 256, 0, stream>>>(Wout, wob, n4o);
    out_gemm<<<dim3(8, 64), 256, 0, stream>>>(ao, wob, out);
}

// Round 11
// 161.644 us; speedup vs baseline: 1.1230x; 1.0068x over previous
//
#include <hip/hip_runtime.h>
#include <hip/hip_bf16.h>

typedef __attribute__((ext_vector_type(4))) float f32x4;
typedef __attribute__((ext_vector_type(8))) short s16x8;
typedef __attribute__((ext_vector_type(4))) short s16x4;

#define DEV static __device__ __forceinline__

// fp32 -> bf16 round-to-nearest-even
DEV unsigned short f2bf(float f) {
    unsigned int u = __builtin_bit_cast(unsigned int, f);
    u += 0x7fffu + ((u >> 16) & 1u);
    return (unsigned short)(u >> 16);
}

#if __has_builtin(__builtin_amdgcn_exp2f)
#define EXP2(x) __builtin_amdgcn_exp2f(x)
#else
#define EXP2(x) exp2f(x)
#endif

// pack two fp32 -> two truncated bf16 in one dword (low short = a, high = b)
DEV unsigned int pack2(float a, float b) {
#if __has_builtin(__builtin_amdgcn_perm)
    return __builtin_amdgcn_perm(__builtin_bit_cast(unsigned int, b),
                                 __builtin_bit_cast(unsigned int, a), 0x07060302u);
#else
    return (__builtin_bit_cast(unsigned int, a) >> 16) |
           (__builtin_bit_cast(unsigned int, b) & 0xffff0000u);
#endif
}

// 8 bf16 from LDS via two 8B reads (strides with only 8B alignment)
DEV s16x8 ld8(const unsigned short* p) {
    s16x4 lo = *(const s16x4*)(p);
    s16x4 hi = *(const s16x4*)(p + 4);
    return __builtin_shufflevector(lo, hi, 0, 1, 2, 3, 4, 5, 6, 7);
}
// 16B-aligned single b128 read
DEV s16x8 ld8a(const unsigned short* p) { return *(const s16x8*)p; }

DEV f32x4 mfma16(s16x8 a, s16x8 b, f32x4 c) {
    return __builtin_amdgcn_mfma_f32_16x16x32_bf16(a, b, c, 0, 0, 0);
}

// async global->LDS, 16B per lane; lds dest = wave-uniform base + lane*16
DEV void glds16(const unsigned short* g, unsigned short* l) {
    __builtin_amdgcn_global_load_lds(
        (const __attribute__((address_space(1))) unsigned int*)g,
        (__attribute__((address_space(3))) unsigned int*)l, 16, 0, 0);
}

// ---------------------------------------------------------------------------
// fp32 -> bf16 bulk cast over three disjoint regions (one launch)
// ---------------------------------------------------------------------------
__global__ __launch_bounds__(256) void convf2b3(
        const float* __restrict__ s0, unsigned short* __restrict__ d0, int n40,
        const float* __restrict__ s1, unsigned short* __restrict__ d1, int n41,
        const float* __restrict__ s2, unsigned short* __restrict__ d2, int n42) {
    int i = blockIdx.x * 256 + threadIdx.x;
    if (i < n40) {
        float4 v = ((const float4*)s0)[i];
        s16x4 o = {(short)f2bf(v.x), (short)f2bf(v.y), (short)f2bf(v.z), (short)f2bf(v.w)};
        ((s16x4*)d0)[i] = o;
    } else if (i - n40 < n41) {
        int j = i - n40;
        float4 v = ((const float4*)s1)[j];
        s16x4 o = {(short)f2bf(v.x), (short)f2bf(v.y), (short)f2bf(v.z), (short)f2bf(v.w)};
        ((s16x4*)d1)[j] = o;
    } else if (i - n40 - n41 < n42) {
        int j = i - n40 - n41;
        float4 v = ((const float4*)s2)[j];
        s16x4 o = {(short)f2bf(v.x), (short)f2bf(v.y), (short)f2bf(v.z), (short)f2bf(v.w)};
        ((s16x4*)d2)[j] = o;
    }
}

__global__ __launch_bounds__(256) void convf2b(const float* __restrict__ s,
                                               unsigned short* __restrict__ d, int n4) {
    int i = blockIdx.x * 256 + threadIdx.x;
    if (i < n4) {
        float4 v = ((const float4*)s)[i];
        s16x4 o = {(short)f2bf(v.x), (short)f2bf(v.y), (short)f2bf(v.z), (short)f2bf(v.w)};
        ((s16x4*)d)[i] = o;
    }
}

// ---------------------------------------------------------------------------
// QKV projection (proven 128x128 2-phase, 768 blocks = 3/CU, ~815 TF):
// C[4096][3072] = Xb[4096][1024](bf16) * Wq[3072][1024](bf16)^T
// ---------------------------------------------------------------------------
__global__ __launch_bounds__(512) void qkv_gemm(
        const unsigned short* __restrict__ Xb, const unsigned short* __restrict__ Wq,
        unsigned short* __restrict__ q_ws, unsigned short* __restrict__ k_ws,
        unsigned short* __restrict__ v_ws) {
    __shared__ unsigned short As[2][128 * 32];
    __shared__ unsigned short Bs[2][128 * 32];
    const int tid = threadIdx.x, lane = tid & 63, wave = tid >> 6;  // 0..7
    const int l15 = lane & 15, l4 = lane >> 4;
    const int wm = (wave >> 1) * 32, wn = (wave & 1) * 64;
    const int m0 = blockIdx.y * 128, n0 = blockIdx.x * 128;

    f32x4 acc[2][4];
    for (int i = 0; i < 2; i++)
        for (int j = 0; j < 4; j++) acc[i][j] = (f32x4){0.f, 0.f, 0.f, 0.f};

    const unsigned short* aptr = &Xb[(size_t)(m0 + wave * 16 + (lane >> 2)) * 1024 + (lane & 3) * 8];
    const unsigned short* bptr = &Wq[(size_t)(n0 + wave * 16 + (lane >> 2)) * 1024 + (lane & 3) * 8];

    for (int k0 = 0; k0 < 1024; k0 += 64) {
        __syncthreads();
        for (int c = 0; c < 2; c++) {
            glds16(aptr + k0 + c * 32, &As[c][(wave * 16) * 32]);
            glds16(bptr + k0 + c * 32, &Bs[c][(wave * 16) * 32]);
        }
        __syncthreads();
        for (int c = 0; c < 2; c++) {
            s16x8 af[2], bf[4];
            for (int mt = 0; mt < 2; mt++) af[mt] = ld8a(&As[c][(wm + mt * 16 + l15) * 32 + l4 * 8]);
            for (int nt = 0; nt < 4; nt++) bf[nt] = ld8a(&Bs[c][(wn + nt * 16 + l15) * 32 + l4 * 8]);
            for (int mt = 0; mt < 2; mt++)
                for (int nt = 0; nt < 4; nt++)
                    acc[mt][nt] = mfma16(af[mt], bf[nt], acc[mt][nt]);
        }
    }

    // epilogue (C/D layout: row=(lane>>4)*4+reg, col=lane&15)
    const int gnb = n0 + wn;  // 64-aligned -> one (which, head) per wave
    const int which = gnb >> 10, h = (gnb >> 6) & 15;
    const int bidx = m0 >> 11, tb = m0 & 2047;
    if (which == 2) {
        // V transposed: v_ws[bh][dh][t], 4 consecutive t per lane -> 8B store
        unsigned short* dst = v_ws + (size_t)(bidx * 16 + h) * 64 * 2048;
        for (int mt = 0; mt < 2; mt++) {
            int t = tb + wm + mt * 16 + l4 * 4;
            for (int nt = 0; nt < 4; nt++) {
                int dh = nt * 16 + l15;
                s16x4 pp;
                for (int r = 0; r < 4; r++) pp[r] = (short)f2bf(acc[mt][nt][r]);
                *(s16x4*)&dst[(size_t)dh * 2048 + t] = pp;
            }
        }
    } else {
        unsigned short* dst = ((which == 0) ? q_ws : k_ws) + (size_t)(bidx * 16 + h) * 2048 * 64;
        // q folded scale: Dh^-0.5 * log2(e) so attention uses raw exp2
        const float sc = (which == 0) ? 0.18033688f : 1.0f;
        for (int mt = 0; mt < 2; mt++) {
            int t0 = tb + wm + mt * 16 + l4 * 4;
            for (int nt = 0; nt < 4; nt++) {
                int dh = nt * 16 + l15;
                for (int r = 0; r < 4; r++)
                    dst[(size_t)(t0 + r) * 64 + dh] = f2bf(acc[mt][nt][r] * sc);
            }
        }
    }
}

// ---------------------------------------------------------------------------
// Causal flash attention v15 = v12 with 2 subtiles per barrier-round.
// Same split-key uniform schedule: block handles chunk pair (p, 15-p),
// group A (waves 0-3) hi-chunk vs subtiles 0..16, group B (waves 4-7)
// lo-chunk (Tlo=2p+2 subtiles) then hi remainder. 17 subtiles/group, paired
// into 9 rounds (Tlo even -> pairs never straddle the lo/hi switch).
// Per-round overhead (~2.2k cy barrier+drain+serial chain) x 9 instead of 17.
// Pipeline 2-deep at pair granularity: stage(pair r+1) right after round r's
// barrier (its buffer was freed by that barrier); full-round compute covers
// the load -> vmcnt(0) drain is free. P: 16 rows/wave, XOR swizzle,
// sequential-qs round-trip (v14 body, proven correct). LDS 144 KB, 1 blk/CU.
// ---------------------------------------------------------------------------
__global__ __launch_bounds__(512, 2) void attn(
        const unsigned short* __restrict__ q_ws, const unsigned short* __restrict__ k_ws,
        const unsigned short* __restrict__ v_ws, unsigned short* __restrict__ ao) {
    // carve: per group, K and V streams of 2 bufs x 2 subtiles x 4096 shorts
    __shared__ unsigned short lds[73728];
    unsigned short* KsA = lds;                 // 16384 shorts
    unsigned short* VtA = lds + 16384;
    unsigned short* KsB = lds + 32768;
    unsigned short* VtB = lds + 49152;
    unsigned short* Ps  = lds + 65536;         // 8 waves x 16 rows x 64

    const int tid = threadIdx.x, lane = tid & 63, wave = tid >> 6;  // 0..7
    const int l15 = lane & 15, l4 = lane >> 4;
    const int xf = (l15 >> 1) & 3;  // K/V read-slot swizzle (matched on glds src)
    const int sw = (l15 & 7) << 3;  // P-region XOR swizzle (shorts)

    const int id = blockIdx.x;
    const int bh8 = id & 7, rest = id >> 3;
    const int p = rest & 7, g = rest >> 3;     // p in [0,8), g in [0,4)
    const int bh = bh8 + 8 * g, b = bh >> 4, h = bh & 15;
    const bool isA = wave < 4;
    const int w4 = wave & 3;
    const int qrow_hi = (15 - p) * 128 + w4 * 32;
    const int qrow_lo = p * 128 + w4 * 32;
    const int Tlo = 2 * p + 2;                 // even, 2..16

    const size_t base = (size_t)bh * 2048 * 64;
    const unsigned short* vtb = v_ws + (size_t)bh * 64 * 2048;  // V^T [d][t]
    unsigned short* Pw = &Ps[wave * 1024];

    // staging: wave stages 16 K rows (seg) + 16 V^T rows per subtile, of ITS
    // GROUP's stream. Source col pre-swizzled to match (l4^xf) read.
    const int seg = w4, srow = lane >> 2;
    const int scol = ((lane & 3) ^ ((lane >> 3) & 3)) * 8;  // shorts
    const unsigned short* kg = &k_ws[base + (size_t)(seg * 16 + srow) * 64 + scol];
    const unsigned short* vg = &vtb[(size_t)(seg * 16 + srow) * 2048 + scol];
    unsigned short* Ksm = isA ? KsA : KsB;
    unsigned short* Vtm = isA ? VtA : VtB;

    auto myTile = [&](int x) { return (isA || x < Tlo) ? x : 17 + x - Tlo; };
    auto stage64 = [&](int t64, int buf, int sub) {  // 4 glds16
        const unsigned short* kgt = kg + (size_t)t64 * 4096;
        const unsigned short* vgt = vg + t64 * 64;
        unsigned short* kd = Ksm + buf * 8192 + sub * 4096 + seg * 512;
        unsigned short* vd = Vtm + buf * 8192 + sub * 4096 + seg * 512;
        glds16(kgt,      kd);
        glds16(kgt + 32, kd + 2048);
        glds16(vgt,      vd);
        glds16(vgt + 32, vd + 2048);
    };

    // Q fragments (B-operand: n=q, k=d); pre-scaled by Dh^-0.5*log2e.
    s16x8 qfh[2][2], qfl[2][2];
#pragma unroll
    for (int qs = 0; qs < 2; qs++)
#pragma unroll
        for (int c = 0; c < 2; c++)
            qfh[qs][c] = ld8a(&q_ws[base + (size_t)(qrow_hi + qs * 16 + l15) * 64 + c * 32 + l4 * 8]);
    if (!isA) {
#pragma unroll
        for (int qs = 0; qs < 2; qs++)
#pragma unroll
            for (int c = 0; c < 2; c++)
                qfl[qs][c] = ld8a(&q_ws[base + (size_t)(qrow_lo + qs * 16 + l15) * 64 + c * 32 + l4 * 8]);
    }
    asm volatile("s_waitcnt vmcnt(0)" ::: "memory");  // clean slate for counts

    f32x4 oh[2][4], ol[2][4];
    float lh[2] = {0.f, 0.f}, ll[2] = {0.f, 0.f};
#pragma unroll
    for (int qs = 0; qs < 2; qs++)
#pragma unroll
        for (int i = 0; i < 4; i++) {
            oh[qs][i] = (f32x4){0.f, 0.f, 0.f, 0.f};
            ol[qs][i] = (f32x4){0.f, 0.f, 0.f, 0.f};
        }

    // v14-style compute body: K/V frags shared across both qs; P 16-row
    // sequential per qs (per-wave in-order DS pipe -> WAR safe).
    auto compute = [&](const unsigned short* kb, const unsigned short* vb,
                       s16x8 (&qf)[2][2], f32x4 (&o)[2][4], float (&ls)[2],
                       int qrow, int k0) {
        f32x4 st[2][4];
#pragma unroll
        for (int qs = 0; qs < 2; qs++)
#pragma unroll
            for (int ks = 0; ks < 4; ks++) st[qs][ks] = (f32x4){0.f, 0.f, 0.f, 0.f};
        __builtin_amdgcn_s_setprio(1);
#pragma unroll
        for (int c = 0; c < 2; c++)
#pragma unroll
            for (int ks = 0; ks < 4; ks++) {
                s16x8 kf = ld8a(&kb[c * 2048 + (ks * 16 + l15) * 32 + (l4 ^ xf) * 8]);
                st[0][ks] = mfma16(kf, qf[0][c], st[0][ks]);
                st[1][ks] = mfma16(kf, qf[1][c], st[1][ks]);
            }
        __builtin_amdgcn_s_setprio(0);

        s16x8 pf[2][2];
#pragma unroll
        for (int qs = 0; qs < 2; qs++) {
            const int qb = qrow + qs * 16;
            if (k0 + 63 > qb) {  // wave-uniform diagonal check
                int qg = qb + l15;
#pragma unroll
                for (int ks = 0; ks < 4; ks++)
#pragma unroll
                    for (int rr = 0; rr < 4; rr++) {
                        int kgi = k0 + ks * 16 + l4 * 4 + rr;
                        if (kgi > qg) st[qs][ks][rr] = -1e30f;
                    }
            }
            float part = 0.f;
#pragma unroll
            for (int ks = 0; ks < 4; ks++) {
                float p0 = EXP2(st[qs][ks][0]);
                float p1 = EXP2(st[qs][ks][1]);
                float p2 = EXP2(st[qs][ks][2]);
                float p3 = EXP2(st[qs][ks][3]);
                part += (p0 + p1) + (p2 + p3);
                unsigned int u0 = pack2(p0, p1), u1 = pack2(p2, p3);
                *(uint2*)&Pw[l15 * 64 + ((ks * 16 + l4 * 4) ^ sw)] = (uint2){u0, u1};
            }
            ls[qs] += part;
#pragma unroll
            for (int c = 0; c < 2; c++)
                pf[qs][c] = ld8(&Pw[l15 * 64 + ((c * 32 + l4 * 8) ^ sw)]);
        }

        __builtin_amdgcn_s_setprio(1);
#pragma unroll
        for (int c = 0; c < 2; c++)
#pragma unroll
            for (int ds = 0; ds < 4; ds++) {
                s16x8 vf = ld8a(&vb[c * 2048 + (ds * 16 + l15) * 32 + (l4 ^ xf) * 8]);
                o[0][ds] = mfma16(vf, pf[0][c], o[0][ds]);
                o[1][ds] = mfma16(vf, pf[1][c], o[1][ds]);
            }
        __builtin_amdgcn_s_setprio(0);
    };

    // prologue: pairs 0 (subtiles 0,1 -> buf0) and 1 (subtiles 2,3 -> buf1)
    stage64(myTile(0), 0, 0);
    stage64(myTile(1), 0, 1);
    stage64(myTile(2), 1, 0);
    stage64(myTile(3), 1, 1);

    for (int r = 0; r < 9; ++r) {
        if (r == 0) asm volatile("s_waitcnt vmcnt(8)" ::: "memory");  // pair 0 done
        else        asm volatile("s_waitcnt vmcnt(0)" ::: "memory");  // pair r done
        __builtin_amdgcn_s_barrier();  // pair r-1's buffer now free
        if (r >= 1 && r + 1 <= 8) {    // stage pair r+1 into the freed buffer
            const int nb = (r + 1) & 1;
            stage64(myTile(2 * (r + 1)), nb, 0);
            if (r + 1 < 8) stage64(myTile(2 * (r + 1) + 1), nb, 1);
        }
#pragma unroll
        for (int j = 0; j < 2; ++j) {
            const int i = 2 * r + j;
            if (i > 16) break;  // round 8 has a single subtile
            const unsigned short* kb = Ksm + (r & 1) * 8192 + j * 4096;
            const unsigned short* vb = Vtm + (r & 1) * 8192 + j * 4096;
            const int k0 = myTile(i) * 64;
            if (isA) {
                if (k0 < qrow_hi + 16) compute(kb, vb, qfh, oh, lh, qrow_hi, k0);
            } else if (i < Tlo) {
                if (k0 < qrow_lo + 16) compute(kb, vb, qfl, ol, ll, qrow_lo, k0);
            } else {
                if (k0 < qrow_hi + 16) compute(kb, vb, qfh, oh, lh, qrow_hi, k0);
            }
        }
    }

    // ---- merge hi-chunk partials (A keys 0..1087 + B keys 1088..) ----
    __syncthreads();  // all K/V reads done; stream area reusable
    float* mrg = (float*)lds;   // per B-wave: 8 f32x4-vecs x 64 lanes + 2x64 l
    f32x4* m4 = (f32x4*)mrg;
    if (!isA) {
#pragma unroll
        for (int qs = 0; qs < 2; qs++) {
#pragma unroll
            for (int ds = 0; ds < 4; ds++)
                m4[w4 * 544 + (qs * 4 + ds) * 64 + lane] = oh[qs][ds];
            mrg[w4 * 2176 + 2048 + qs * 64 + lane] = lh[qs];
        }
    }
    __syncthreads();

    auto epilogue = [&](f32x4 (&o)[2][4], float (&ls)[2], int qrow) {
        int qr = lane >> 2, qt = lane & 3;
        const int swr = (qr & 7) << 3;
#pragma unroll
        for (int qs = 0; qs < 2; qs++) {
            float t = ls[qs];
            t += __shfl_xor(t, 16, 64);
            t += __shfl_xor(t, 32, 64);
            float inv = 1.f / t;
#pragma unroll
            for (int ds = 0; ds < 4; ds++) {
                s16x4 pp;
#pragma unroll
                for (int r = 0; r < 4; r++) pp[r] = (short)f2bf(o[qs][ds][r] * inv);
                *(s16x4*)&Pw[l15 * 64 + ((ds * 16 + l4 * 4) ^ sw)] = pp;  // Ow[q][d]
            }
            size_t orow = ((size_t)b * 2048 + qrow + qs * 16 + qr) * 1024 + h * 64 + qt * 16;
            *(s16x8*)&ao[orow]     = ld8(&Pw[qr * 64 + ((qt * 16) ^ swr)]);
            *(s16x8*)&ao[orow + 8] = ld8(&Pw[qr * 64 + ((qt * 16 + 8) ^ swr)]);
        }
    };

    if (isA) {
#pragma unroll
        for (int qs = 0; qs < 2; qs++) {
#pragma unroll
            for (int ds = 0; ds < 4; ds++)
                oh[qs][ds] += m4[w4 * 544 + (qs * 4 + ds) * 64 + lane];
            lh[qs] += mrg[w4 * 2176 + 2048 + qs * 64 + lane];
        }
        epilogue(oh, lh, qrow_hi);
    } else {
        epilogue(ol, ll, qrow_lo);
    }
}

// ---------------------------------------------------------------------------
// Output projection v2 (round-6 win, frozen): OUT = AO(bf16) * Wo(bf16)^T.
// 64(M)x128(N) block tile, 256 thr / 4 waves, wave tile 32x64, BK=64.
// Grid (8 n, 64 m) = 512 blocks = 2/CU.
// ---------------------------------------------------------------------------
__global__ __launch_bounds__(256) void out_gemm(
        const unsigned short* __restrict__ A, const unsigned short* __restrict__ Bm,
        float* __restrict__ OUT) {
    __shared__ unsigned short As[2][64 * 32];
    __shared__ unsigned short Bs[2][128 * 32];
    const int tid = threadIdx.x, lane = tid & 63, wave = tid >> 6;  // 0..3
    const int l15 = lane & 15, l4 = lane >> 4;
    const int wm = (wave >> 1) * 32, wn = (wave & 1) * 64;
    const int m0 = blockIdx.y * 64, n0 = blockIdx.x * 128;

    f32x4 acc[2][4];
    for (int i = 0; i < 2; i++)
        for (int j = 0; j < 4; j++) acc[i][j] = (f32x4){0.f, 0.f, 0.f, 0.f};

    // wave stages A rows [wave*16,+16) and B rows [wave*32,+32)
    const unsigned short* aptr = &A[(size_t)(m0 + wave * 16 + (lane >> 2)) * 1024 + (lane & 3) * 8];
    const unsigned short* bptr = &Bm[(size_t)(n0 + wave * 32 + (lane >> 2)) * 1024 + (lane & 3) * 8];

    for (int k0 = 0; k0 < 1024; k0 += 64) {
        __syncthreads();
        for (int c = 0; c < 2; c++) {
            glds16(aptr + k0 + c * 32, &As[c][(wave * 16) * 32]);
            glds16(bptr + k0 + c * 32, &Bs[c][(wave * 32) * 32]);
            glds16(bptr + k0 + c * 32 + 16 * 1024, &Bs[c][(wave * 32 + 16) * 32]);
        }
        __syncthreads();
        for (int c = 0; c < 2; c++) {
            s16x8 af[2], bf[4];
            for (int mt = 0; mt < 2; mt++) af[mt] = ld8a(&As[c][(wm + mt * 16 + l15) * 32 + l4 * 8]);
            for (int nt = 0; nt < 4; nt++) bf[nt] = ld8a(&Bs[c][(wn + nt * 16 + l15) * 32 + l4 * 8]);
            for (int mt = 0; mt < 2; mt++)
                for (int nt = 0; nt < 4; nt++)
                    acc[mt][nt] = mfma16(af[mt], bf[nt], acc[mt][nt]);
        }
    }

    for (int mt = 0; mt < 2; mt++)
        for (int nt = 0; nt < 4; nt++)
            for (int r = 0; r < 4; r++) {
                int gm = m0 + wm + mt * 16 + l4 * 4 + r;
                int gn = n0 + wn + nt * 16 + l15;
                OUT[(size_t)gm * 1024 + gn] = acc[mt][nt][r];
            }
}

// ---------------------------------------------------------------------------
extern "C" void kernel_launch(void* const* d_in, const int* in_sizes, int n_in,
                              void* d_out, int out_size, void* d_ws, size_t ws_size,
                              hipStream_t stream) {
    (void)in_sizes; (void)n_in; (void)out_size;
    const float* x    = (const float*)d_in[0];   // [2,2048,1024]
    const float* Wqkv = (const float*)d_in[1];   // [3072,1024]
    const float* Wout = (const float*)d_in[2];   // [1024,1024]
    float* out = (float*)d_out;                  // [2,2048,1024] fp32

    // workspace layout (first 32 MB):
    //   [0,8M)   q_ws [bh][T][64]
    //   [8,16M)  k_ws [bh][T][64]
    //   [16,24M) v_ws TRANSPOSED [bh][64][T]
    //   [24,32M) Xb (bf16 X) during qkv; then attn output AO
    //   [32M,34M) wob (Wout bf16) if ws_size permits
    // d_out (16 MB fp32) doubles as scratch for Wqkv-bf16 (6 MB).
    unsigned short* q_ws = (unsigned short*)d_ws;
    unsigned short* k_ws = q_ws + (size_t)4 * 1024 * 1024;
    unsigned short* v_ws = k_ws + (size_t)4 * 1024 * 1024;
    unsigned short* xb   = v_ws + (size_t)4 * 1024 * 1024;  // 8 MB
    unsigned short* ao   = xb;                              // born in attn, xb dead
    unsigned short* wqb  = (unsigned short*)d_out;          // 6 MB scratch in d_out

    const int n4x = 2 * 2048 * 1024 / 4, n4w = 3072 * 1024 / 4, n4o = 1024 * 1024 / 4;
    const bool merged = ws_size >= (size_t)35 * 1024 * 1024;
    unsigned short* wob = merged ? (q_ws + (size_t)16 * 1024 * 1024)  // d_ws + 32 MB
                                 : q_ws;                              // reuse after attn

    if (merged) {
        convf2b3<<<(n4x + n4w + n4o + 255) / 256, 256, 0, stream>>>(
            x, xb, n4x, Wqkv, wqb, n4w, Wout, wob, n4o);
    } else {
        convf2b3<<<(n4x + n4w + 255) / 256, 256, 0, stream>>>(
            x, xb, n4x, Wqkv, wqb, n4w, Wout, wob, 0);
    }
    qkv_gemm<<<dim3(24, 32), 512, 0, stream>>>(xb, wqb, q_ws, k_ws, v_ws);
    attn<<<dim3(256), 512, 0, stream>>>(q_ws, k_ws, v_ws, ao);
    if (!merged) convf2b<<<1024, 256, 0, stream>>>(Wout, wob, n4o);
    out_gemm<<<dim3(8, 64), 256, 0, stream>>>(ao, wob, out);
}